// Round 6
// baseline (1331.975 us; speedup 1.0000x reference)
//
#include <hip/hip_runtime.h>

#define T_LEN 2048
#define NMODE 8
#define NPP   17   // 8 tau + 9 g (g[0]=g_infy)
#define AGENT __HIP_MEMORY_SCOPE_AGENT

// ---------------------------------------------------------------------------
// Single-pass Prony scan with decoupled lookback.
// One block (128 thr) per (b, chunk of L timesteps); virtual block id via
// atomic ticket (scheduling-order => lookback is deadlock-free). Lane tid<72
// owns (e=tid/8, m=tid&7). Local recurrence runs from LDS-staged inputs;
// per-chunk transform is diagonal-affine per (e,m): (P[m], R[e,m]).
// Flags: poison 0xAAAAAAAA = not-ready; 1 = partial ready; 2 = prefix ready.
// Prefix applied algebraically: Q_t = Qloc_t + cumA_t[m]*Z[e,m].
// ---------------------------------------------------------------------------
template <int L>
__global__ __launch_bounds__(128)
void prony_lookback(const float* __restrict__ Se,   // [B,T,3,3]
                    const float* __restrict__ tt,   // [B,T]
                    const float* __restrict__ pp,   // [B,T,17]
                    float* __restrict__ out,        // [3,B,T,3,3]
                    int*   __restrict__ counter,
                    int*   __restrict__ flags,      // [B*NC]
                    float* __restrict__ partP,      // [B*NC,8]
                    float* __restrict__ partR,      // [B*NC,72]
                    float* __restrict__ prefR,      // [B*NC,72]
                    int B) {
    constexpr int NC = T_LEN / L;
    const int tid = threadIdx.x;

    __shared__ float s_pp[(L + 1) * NPP];
    __shared__ float s_Se[(L + 1) * 9];
    __shared__ float s_t[L + 1];
    __shared__ float s_inv[L + 1];
    __shared__ float s_o0[L * 9];
    __shared__ float s_o1[L * 9];
    __shared__ float s_o2[L * 9];
    __shared__ int   s_word;

    if (tid == 0) s_word = atomicAdd(counter, 1);
    __syncthreads();
    const int v  = s_word;
    const int b  = v % B;          // c-major: predecessors ticketed B earlier
    const int c  = v / B;
    const int t0 = c * L;
    const int r0 = (c == 0) ? 0 : t0 - 1;
    const int off = (c == 0) ? 0 : 1;

    // ---- stage inputs (contiguous segments, coalesced) ----
    {
        const float* src = pp + ((size_t)b * T_LEN + r0) * NPP;
        for (int i = tid; i < (L + 1) * NPP; i += 128) s_pp[i] = src[i];
        const float* ss = Se + ((size_t)b * T_LEN + r0) * 9;
        for (int i = tid; i < (L + 1) * 9; i += 128) s_Se[i] = ss[i];
        const float* st = tt + ((size_t)b * T_LEN + r0);
        if (tid < L + 1) s_t[tid] = st[tid];
    }
    __syncthreads();
    if (tid < L + 1) {
        float g = 0.f;
        #pragma unroll
        for (int k = 8; k < NPP; ++k) g += s_pp[tid * NPP + k];
        s_inv[tid] = __builtin_amdgcn_rcpf(g);
    }
    __syncthreads();

    const bool act = tid < 72;
    const int  e   = act ? (tid >> 3) : 0;
    const int  m   = tid & 7;

    // ---- previous-row state ----
    float tau_p = s_pp[m];
    float gq_p  = s_pp[9 + m] * s_inv[0];
    float t_p   = (c == 0) ? -tt[(size_t)b * T_LEN + 1] : s_t[0];
    float S_p   = (c == 0) ? 0.f : s_Se[e];

    // ---- local scan from zero state ----
    float Q = 0.f, cA = 1.f;
    float caA[L];
    #pragma unroll
    for (int s = 0; s < L; ++s) {
        const int rc = s + off;
        float tau_c = s_pp[rc * NPP + m];
        float inv_c = s_inv[rc];
        float gq_c  = s_pp[rc * NPP + 9 + m] * inv_c;
        float t_c   = s_t[rc];
        float S_c   = s_Se[rc * 9 + e];
        float ee = __expf((t_p - t_c) * __builtin_amdgcn_rcpf(tau_c + tau_p));
        float A  = ee * ee;
        float eC = ee * 0.5f * (gq_c + gq_p);
        Q   = A * Q + eC * (S_c - S_p);
        cA *= A;
        caA[s] = cA;
        float qs = Q;                       // sum over m within 8-lane group
        qs += __shfl_xor(qs, 1);
        qs += __shfl_xor(qs, 2);
        qs += __shfl_xor(qs, 4);
        if (act && m == 0) {
            float sf = s_pp[rc * NPP + 8] * inv_c * S_c;   // g_infy/sum * S_e
            s_o1[s * 9 + e] = sf;           // S_infy
            s_o2[s * 9 + e] = qs;           // local qsum (prefix corr later)
        }
        tau_p = tau_c; gq_p = gq_c; t_p = t_c; S_p = S_c;
    }

    // ---- publish partial transform ----
    const size_t sb = (size_t)b * NC + c;
    if (act)
        __hip_atomic_store(&partR[sb * 72 + tid], Q, __ATOMIC_RELAXED, AGENT);
    if (act && e == 0)
        __hip_atomic_store(&partP[sb * 8 + m], cA, __ATOMIC_RELAXED, AGENT);
    __syncthreads();                         // drain all lanes' stores
    if (c > 0 && tid == 0)
        __hip_atomic_store(&flags[sb], 1, __ATOMIC_RELEASE, AGENT);

    // ---- decoupled lookback: compute Z = state entering this chunk ----
    float Z = 0.f;
    if (c > 0) {
        float Pacc = 1.f, Racc = 0.f;
        int j = c - 1;
        for (;;) {
            __syncthreads();                 // protect s_word reuse
            if (tid == 0) {
                int f;
                do {
                    f = __hip_atomic_load(&flags[(size_t)b * NC + j],
                                          __ATOMIC_ACQUIRE, AGENT);
                } while (f != 1 && f != 2);
                s_word = f;
            }
            __syncthreads();
            const int f = s_word;
            const size_t jb = (size_t)b * NC + j;
            if (f == 2) {
                float pr = act ? __hip_atomic_load(&prefR[jb * 72 + tid],
                                                   __ATOMIC_RELAXED, AGENT) : 0.f;
                Z = Pacc * pr + Racc;
                break;
            }
            float rj = act ? __hip_atomic_load(&partR[jb * 72 + tid],
                                               __ATOMIC_RELAXED, AGENT) : 0.f;
            float pj = __hip_atomic_load(&partP[jb * 8 + m],
                                         __ATOMIC_RELAXED, AGENT);
            Racc = Pacc * rj + Racc;
            Pacc = Pacc * pj;
            --j;
        }
    }

    // ---- publish inclusive prefix state (successors unblock ASAP) ----
    if (act)
        __hip_atomic_store(&prefR[sb * 72 + tid], Q + cA * Z,
                           __ATOMIC_RELAXED, AGENT);
    __syncthreads();
    if (tid == 0)
        __hip_atomic_store(&flags[sb], 2, __ATOMIC_RELEASE, AGENT);

    // ---- apply prefix correction: corr_t[e] = sum_m cumA_t[m]*Z[e,m] ----
    #pragma unroll
    for (int s = 0; s < L; ++s) {
        float corr = caA[s] * Z;
        corr += __shfl_xor(corr, 1);
        corr += __shfl_xor(corr, 2);
        corr += __shfl_xor(corr, 4);
        if (act && m == 0) {
            float qs = s_o2[s * 9 + e] + corr;
            s_o2[s * 9 + e] = qs;                      // Q_sum
            s_o0[s * 9 + e] = s_o1[s * 9 + e] + qs;    // S
        }
    }
    __syncthreads();

    // ---- coalesced output write (3 contiguous 576B segments) ----
    const size_t nOut = (size_t)B * T_LEN * 9;
    float* o = out + ((size_t)b * T_LEN + t0) * 9;
    for (int i = tid; i < L * 9; i += 128) {
        o[i]            = s_o0[i];
        o[nOut + i]     = s_o1[i];
        o[2 * nOut + i] = s_o2[i];
    }
}

__global__ void init_counter(int* counter) {
    if (threadIdx.x == 0) *counter = 0;
}

// ---------------------------------------------------------------------------
template <int L>
static void run(const float* Se, const float* tt, const float* pp, float* out,
                void* d_ws, int B, hipStream_t stream) {
    constexpr int NC = T_LEN / L;
    const size_t BNC = (size_t)B * NC;
    int* ws_i    = (int*)d_ws;
    int* counter = ws_i;
    int* flags   = ws_i + 64;                  // keep counter on its own line
    float* partP = (float*)(flags + BNC);
    float* partR = partP + BNC * 8;
    float* prefR = partR + BNC * 72;

    init_counter<<<1, 64, 0, stream>>>(counter);
    prony_lookback<L><<<(int)BNC, dim3(128), 0, stream>>>(
        Se, tt, pp, out, counter, flags, partP, partR, prefR, B);
}

extern "C" void kernel_launch(void* const* d_in, const int* in_sizes, int n_in,
                              void* d_out, int out_size, void* d_ws, size_t ws_size,
                              hipStream_t stream) {
    const float* Se = (const float*)d_in[0];
    const float* tt = (const float*)d_in[1];
    const float* pp = (const float*)d_in[2];
    float* out = (float*)d_out;

    int B = in_sizes[1] / T_LEN;

    auto need = [&](int NC) {
        return (64 + (size_t)B * NC) * sizeof(int)
             + (size_t)B * NC * (8 + 72 + 72) * sizeof(float);
    };

    if (need(T_LEN / 16) <= ws_size) {
        run<16>(Se, tt, pp, out, d_ws, B, stream);   // NC=128
    } else {
        run<64>(Se, tt, pp, out, d_ws, B, stream);   // NC=32, tiny state
    }
}

// Round 7
// 135.023 us; speedup vs baseline: 9.8648x; 9.8648x over previous
//
#include <hip/hip_runtime.h>

#define T_LEN 2048
#define NMODE 8
#define NPP   17   // 8 tau + 9 g (g[0]=g_infy)

// ---------------------------------------------------------------------------
// Phase A: one block (128 thr) per (b, chunk of L steps). Lane tid<72 owns
// (e=tid>>3, m=tid&7). Inputs LDS-staged (contiguous, coalesced). Local
// recurrence from zero state. Writes:
//   out plane1 = S_infy (final), out plane2 = local qsum (corrected in C),
//   partR[b,e,c,m] = local chunk result, partP[b,c,m] = prod(A) over chunk,
//   caA[b,c,s,m]  = cumulative prod of A within chunk (for phase C algebra).
// ---------------------------------------------------------------------------
template <int L>
__global__ __launch_bounds__(128)
void phaseA(const float* __restrict__ Se,   // [B,T,3,3]
            const float* __restrict__ tt,   // [B,T]
            const float* __restrict__ pp,   // [B,T,17]
            float* __restrict__ out,        // [3,B,T,3,3]
            float* __restrict__ partR,      // [B,9,NC,8]
            float* __restrict__ partP,      // [B,NC,8]
            float* __restrict__ caA,        // [B,NC,L,8]
            int B) {
    constexpr int NC = T_LEN / L;
    const int tid = threadIdx.x;
    const int c   = blockIdx.x % NC;
    const int b   = blockIdx.x / NC;
    const int t0  = c * L;
    const int r0  = (c == 0) ? 0 : t0 - 1;
    const int off = (c == 0) ? 0 : 1;

    __shared__ float s_pp[(L + 1) * NPP];
    __shared__ float s_Se[(L + 1) * 9];
    __shared__ float s_t[L + 1];
    __shared__ float s_inv[L + 1];
    __shared__ float s_sf[L * 9];     // S_infy
    __shared__ float s_q[L * 9];      // local qsum
    __shared__ float s_ca[L * 8];     // cumA

    {
        const float* src = pp + ((size_t)b * T_LEN + r0) * NPP;
        for (int i = tid; i < (L + 1) * NPP; i += 128) s_pp[i] = src[i];
        const float* ss = Se + ((size_t)b * T_LEN + r0) * 9;
        for (int i = tid; i < (L + 1) * 9; i += 128) s_Se[i] = ss[i];
        const float* st = tt + ((size_t)b * T_LEN + r0);
        if (tid < L + 1) s_t[tid] = st[tid];
    }
    __syncthreads();
    if (tid < L + 1) {
        float g = 0.f;
        #pragma unroll
        for (int k = 8; k < NPP; ++k) g += s_pp[tid * NPP + k];
        s_inv[tid] = __builtin_amdgcn_rcpf(g);
    }
    __syncthreads();

    const bool act = tid < 72;
    const int  e   = tid >> 3;
    const int  m   = tid & 7;

    float tau_p = s_pp[m];
    float gq_p  = s_pp[9 + m] * s_inv[0];
    float t_p   = (c == 0) ? -tt[(size_t)b * T_LEN + 1] : s_t[0];
    float S_p   = (c == 0) ? 0.f : (act ? s_Se[e] : 0.f);

    float Q = 0.f, cA = 1.f;
    #pragma unroll
    for (int s = 0; s < L; ++s) {
        const int rc = s + off;
        float tau_c = s_pp[rc * NPP + m];
        float inv_c = s_inv[rc];
        float gq_c  = s_pp[rc * NPP + 9 + m] * inv_c;
        float t_c   = s_t[rc];
        float S_c   = act ? s_Se[rc * 9 + e] : 0.f;
        float ee = __expf((t_p - t_c) * __builtin_amdgcn_rcpf(tau_c + tau_p));
        float A  = ee * ee;
        float eC = ee * 0.5f * (gq_c + gq_p);
        Q   = A * Q + eC * (S_c - S_p);
        cA *= A;
        float qs = Q;
        qs += __shfl_xor(qs, 1);
        qs += __shfl_xor(qs, 2);
        qs += __shfl_xor(qs, 4);
        if (act && m == 0) {
            s_sf[s * 9 + e] = s_pp[rc * NPP + 8] * inv_c * S_c;
            s_q[s * 9 + e]  = qs;
        }
        if (tid < 8) s_ca[s * 8 + m] = cA;
        tau_p = tau_c; gq_p = gq_c; t_p = t_c; S_p = S_c;
    }

    // partR / partP (small scattered segments, 32B each)
    if (act) partR[((size_t)(b * 9 + e) * NC + c) * 8 + m] = Q;
    if (tid < 8) partP[((size_t)b * NC + c) * 8 + m] = cA;

    __syncthreads();

    // coalesced bulk writes
    const size_t nOut = (size_t)B * T_LEN * 9;
    float* o = out + ((size_t)b * T_LEN + t0) * 9;
    for (int i = tid; i < L * 9; i += 128) {
        o[nOut + i]     = s_sf[i];
        o[2 * nOut + i] = s_q[i];
    }
    float* ca = caA + ((size_t)b * NC + c) * (L * 8);
    for (int i = tid; i < L * 8; i += 128) ca[i] = s_ca[i];
}

// ---------------------------------------------------------------------------
// Phase B: inter-chunk scan, ONE WAVE per (b,e) (proven in R4/R5). Converts
// partR in place from local chunk results to entering states Z (exclusive).
// ---------------------------------------------------------------------------
template <int K>
__global__ __launch_bounds__(256)
void chunk_scan_wave(float* __restrict__ R, const float* __restrict__ P,
                     int B) {
    constexpr int NC = K * 64;
    int gtid = blockIdx.x * blockDim.x + threadIdx.x;
    int wid  = gtid >> 6;
    int lane = gtid & 63;
    if (wid >= B * 9) return;
    int e = wid % 9;
    int b = wid / 9;

    float* rp       = R + ((size_t)(b * 9 + e) * NC) * NMODE;
    const float* pq = P + ((size_t)b * NC) * NMODE;

    float pk[K][NMODE], rk[K][NMODE];
    float pa[NMODE], ra[NMODE];
    #pragma unroll
    for (int m = 0; m < NMODE; ++m) { pa[m] = 1.f; ra[m] = 0.f; }

    #pragma unroll
    for (int k = 0; k < K; ++k) {
        int c = lane * K + k;
        const float4* rv = (const float4*)(rp + (size_t)c * NMODE);
        const float4* pv = (const float4*)(pq + (size_t)c * NMODE);
        float4 r0 = rv[0], r1 = rv[1], p0 = pv[0], p1 = pv[1];
        rk[k][0]=r0.x; rk[k][1]=r0.y; rk[k][2]=r0.z; rk[k][3]=r0.w;
        rk[k][4]=r1.x; rk[k][5]=r1.y; rk[k][6]=r1.z; rk[k][7]=r1.w;
        pk[k][0]=p0.x; pk[k][1]=p0.y; pk[k][2]=p0.z; pk[k][3]=p0.w;
        pk[k][4]=p1.x; pk[k][5]=p1.y; pk[k][6]=p1.z; pk[k][7]=p1.w;
        #pragma unroll
        for (int m = 0; m < NMODE; ++m) {
            ra[m] = pk[k][m] * ra[m] + rk[k][m];
            pa[m] = pk[k][m] * pa[m];
        }
    }

    #pragma unroll
    for (int d = 1; d < 64; d <<= 1) {
        #pragma unroll
        for (int m = 0; m < NMODE; ++m) {
            float plo = __shfl_up(pa[m], d);
            float rlo = __shfl_up(ra[m], d);
            if (lane >= d) {
                ra[m] = pa[m] * rlo + ra[m];
                pa[m] = pa[m] * plo;
            }
        }
    }

    float z[NMODE];
    #pragma unroll
    for (int m = 0; m < NMODE; ++m) {
        float zz = __shfl_up(ra[m], 1);
        z[m] = (lane == 0) ? 0.f : zz;
    }

    #pragma unroll
    for (int k = 0; k < K; ++k) {
        int c = lane * K + k;
        float4* rv = (float4*)(rp + (size_t)c * NMODE);
        rv[0] = make_float4(z[0], z[1], z[2], z[3]);
        rv[1] = make_float4(z[4], z[5], z[6], z[7]);
        #pragma unroll
        for (int m = 0; m < NMODE; ++m)
            z[m] = pk[k][m] * z[m] + rk[k][m];
    }
}

// ---------------------------------------------------------------------------
// Phase C: one block per (b,c). Applies corr_t[e] = sum_m caA[t,m]*Z[e,m]
// to the staged local qsum; writes final S and Q_sum planes. Pure algebra,
// no exp, all traffic coalesced via LDS.
// ---------------------------------------------------------------------------
template <int L>
__global__ __launch_bounds__(128)
void phaseC(float* __restrict__ out,
            const float* __restrict__ partR,   // now Z [b,9,NC,8]
            const float* __restrict__ caA,     // [B,NC,L,8]
            int B) {
    constexpr int NC = T_LEN / L;
    const int tid = threadIdx.x;
    const int c   = blockIdx.x % NC;
    const int b   = blockIdx.x / NC;

    __shared__ float s_Z[72];
    __shared__ float s_ca[L * 8];
    __shared__ float s_q[L * 9];
    __shared__ float s_sf[L * 9];

    if (tid < 72) {
        int e = tid >> 3, m = tid & 7;
        s_Z[tid] = partR[((size_t)(b * 9 + e) * NC + c) * 8 + m];
    }
    const float* ca = caA + ((size_t)b * NC + c) * (L * 8);
    for (int i = tid; i < L * 8; i += 128) s_ca[i] = ca[i];

    const size_t nOut = (size_t)B * T_LEN * 9;
    float* o = out + ((size_t)b * T_LEN + (size_t)c * L) * 9;
    for (int i = tid; i < L * 9; i += 128) {
        s_sf[i] = o[nOut + i];
        s_q[i]  = o[2 * nOut + i];
    }
    __syncthreads();

    for (int i = tid; i < L * 9; i += 128) {
        int t = i / 9, e = i - t * 9;
        float corr = 0.f;
        #pragma unroll
        for (int m = 0; m < NMODE; ++m)
            corr += s_ca[t * 8 + m] * s_Z[e * 8 + m];
        float qs = s_q[i] + corr;
        o[i]            = s_sf[i] + qs;   // S
        o[2 * nOut + i] = qs;             // Q_sum
    }
}

// ---------------------------------------------------------------------------
extern "C" void kernel_launch(void* const* d_in, const int* in_sizes, int n_in,
                              void* d_out, int out_size, void* d_ws, size_t ws_size,
                              hipStream_t stream) {
    const float* Se = (const float*)d_in[0];
    const float* tt = (const float*)d_in[1];
    const float* pp = (const float*)d_in[2];
    float* out = (float*)d_out;

    int B = in_sizes[1] / T_LEN;

    constexpr int L  = 16;
    constexpr int NC = T_LEN / L;     // 128
    constexpr int K  = NC / 64;       // 2

    float* partR = (float*)d_ws;                                  // B*9*NC*8
    float* partP = partR + (size_t)B * 9 * NC * 8;                // B*NC*8
    float* caA   = partP + (size_t)B * NC * 8;                    // B*NC*L*8

    int gridA = B * NC;
    int gridB = (B * 9 * 64 + 255) / 256;

    phaseA<L><<<gridA, dim3(128), 0, stream>>>(Se, tt, pp, out,
                                               partR, partP, caA, B);
    chunk_scan_wave<K><<<gridB, dim3(256), 0, stream>>>(partR, partP, B);
    phaseC<L><<<gridA, dim3(128), 0, stream>>>(out, partR, caA, B);
}

// Round 8
// 130.489 us; speedup vs baseline: 10.2076x; 1.0347x over previous
//
#include <hip/hip_runtime.h>

#define T_LEN 2048
#define NMODE 8
#define NPP   17   // 8 tau + 9 g (g[0]=g_infy)

// ---------------------------------------------------------------------------
// Phase A: block = 72*CPB threads (CPB chunks of L steps, 100% lane util).
// Lane = (chunk k = tid/72, e = (tid%72)>>3, m = tid&7). Stages CPB*L+1
// contiguous input rows in LDS, precomputes per-row (tau, 0.5*g/sum) pairs,
// g_infy/sum; runs the local recurrence from zero state. Writes:
//   out plane1 = S_infy (final), plane2 = local qsum (corrected in phaseC),
//   partR[b,e,c,m] local result, partP[b,c,m] = prod A, caA[b,c,s,m] = cum A.
// ---------------------------------------------------------------------------
template <int L, int CPB>
__global__ __launch_bounds__(72 * CPB)
void phaseA(const float* __restrict__ Se,   // [B,T,3,3]
            const float* __restrict__ tt,   // [B,T]
            const float* __restrict__ pp,   // [B,T,17]
            float* __restrict__ out,        // [3,B,T,3,3]
            float* __restrict__ partR,      // [B,9,NC,8]
            float* __restrict__ partP,      // [B,NC,8]
            float* __restrict__ caA,        // [B,NC,L,8]
            int B) {
    constexpr int NC = T_LEN / L;
    constexpr int NT = 72 * CPB;
    constexpr int RW = CPB * L + 1;

    const int tid  = threadIdx.x;
    const int ngrp = NC / CPB;
    const int b    = blockIdx.x / ngrp;
    const int g    = blockIdx.x % ngrp;
    const int c0   = g * CPB;
    const int base = c0 * L;
    const int off  = (base == 0) ? 0 : 1;
    const int r0   = (base == 0) ? 0 : base - 1;

    __shared__ float2 s_tg[RW * 8];          // (tau, 0.5*g/sum)
    __shared__ float  s_S[RW * 9];
    __shared__ float  s_t[RW];
    __shared__ float  s_inv[RW];
    __shared__ float  s_gi[RW];              // g_infy/sum
    __shared__ float  s_raw[RW * NPP];
    __shared__ float  s_sf[CPB * L * 9];
    __shared__ float  s_q[CPB * L * 9];
    __shared__ float  s_ca[CPB * L * 8];

    {
        const float* pr = pp + ((size_t)b * T_LEN + r0) * NPP;
        for (int i = tid; i < RW * NPP; i += NT) s_raw[i] = pr[i];
        const float* sr = Se + ((size_t)b * T_LEN + r0) * 9;
        for (int i = tid; i < RW * 9; i += NT) s_S[i] = sr[i];
        const float* tr = tt + (size_t)b * T_LEN + r0;
        for (int i = tid; i < RW; i += NT) s_t[i] = tr[i];
    }
    __syncthreads();
    if (tid < RW) {
        float gs = 0.f;
        #pragma unroll
        for (int k = 8; k < NPP; ++k) gs += s_raw[tid * NPP + k];
        float iv = __builtin_amdgcn_rcpf(gs);
        s_inv[tid] = iv;
        s_gi[tid]  = s_raw[tid * NPP + 8] * iv;
    }
    __syncthreads();
    for (int i = tid; i < RW * 8; i += NT) {
        int r = i >> 3, m = i & 7;
        s_tg[i] = make_float2(s_raw[r * NPP + m],
                              0.5f * s_raw[r * NPP + 9 + m] * s_inv[r]);
    }
    __syncthreads();

    const int k  = tid / 72;
    const int u  = tid % 72;
    const int e  = u >> 3;
    const int m  = u & 7;
    const int cg = c0 + k;
    const int pk = (cg == 0) ? 0 : (k * L + off - 1);

    float2 tgp   = s_tg[pk * 8 + m];
    float tau_p  = tgp.x, gqh_p = tgp.y;
    float t_p    = (cg == 0) ? -tt[(size_t)b * T_LEN + 1] : s_t[pk];
    float S_p    = (cg == 0) ? 0.f : s_S[pk * 9 + e];

    float Q = 0.f, cA = 1.f;
    #pragma unroll
    for (int s = 0; s < L; ++s) {
        const int rc = k * L + s + off;
        float2 tg = s_tg[rc * 8 + m];
        float t_c = s_t[rc];
        float S_c = s_S[rc * 9 + e];
        float ee  = __expf((t_p - t_c) * __builtin_amdgcn_rcpf(tg.x + tau_p));
        float A   = ee * ee;
        float eC  = ee * (tg.y + gqh_p);
        Q  = A * Q + eC * (S_c - S_p);
        cA *= A;
        float qs = Q;
        qs += __shfl_xor(qs, 1);
        qs += __shfl_xor(qs, 2);
        qs += __shfl_xor(qs, 4);
        const int ts = k * L + s;
        if (m == 0) {
            s_sf[ts * 9 + e] = s_gi[rc] * S_c;
            s_q [ts * 9 + e] = qs;
        }
        if (u < 8) s_ca[ts * 8 + m] = cA;
        tau_p = tg.x; gqh_p = tg.y; t_p = t_c; S_p = S_c;
    }

    partR[((size_t)(b * 9 + e) * NC + cg) * 8 + m] = Q;
    if (u < 8) partP[((size_t)b * NC + cg) * 8 + m] = cA;
    __syncthreads();

    const size_t nOut = (size_t)B * T_LEN * 9;
    float* o = out + ((size_t)b * T_LEN + base) * 9;
    for (int i = tid; i < CPB * L * 9; i += NT) {
        o[nOut + i]     = s_sf[i];
        o[2 * nOut + i] = s_q[i];
    }
    float* ca = caA + ((size_t)b * NC + c0) * (L * 8);
    for (int i = tid; i < CPB * L * 8; i += NT) ca[i] = s_ca[i];
}

// ---------------------------------------------------------------------------
// Phase B: inter-chunk scan, ONE WAVE per (b,e) (proven R4/R7). Converts
// partR in place from local chunk results to entering states Z (exclusive).
// ---------------------------------------------------------------------------
template <int K>
__global__ __launch_bounds__(256)
void chunk_scan_wave(float* __restrict__ R, const float* __restrict__ P,
                     int B) {
    constexpr int NC = K * 64;
    int gtid = blockIdx.x * blockDim.x + threadIdx.x;
    int wid  = gtid >> 6;
    int lane = gtid & 63;
    if (wid >= B * 9) return;
    int e = wid % 9;
    int b = wid / 9;

    float* rp       = R + ((size_t)(b * 9 + e) * NC) * NMODE;
    const float* pq = P + ((size_t)b * NC) * NMODE;

    float pk[K][NMODE], rk[K][NMODE];
    float pa[NMODE], ra[NMODE];
    #pragma unroll
    for (int m = 0; m < NMODE; ++m) { pa[m] = 1.f; ra[m] = 0.f; }

    #pragma unroll
    for (int k = 0; k < K; ++k) {
        int c = lane * K + k;
        const float4* rv = (const float4*)(rp + (size_t)c * NMODE);
        const float4* pv = (const float4*)(pq + (size_t)c * NMODE);
        float4 r0 = rv[0], r1 = rv[1], p0 = pv[0], p1 = pv[1];
        rk[k][0]=r0.x; rk[k][1]=r0.y; rk[k][2]=r0.z; rk[k][3]=r0.w;
        rk[k][4]=r1.x; rk[k][5]=r1.y; rk[k][6]=r1.z; rk[k][7]=r1.w;
        pk[k][0]=p0.x; pk[k][1]=p0.y; pk[k][2]=p0.z; pk[k][3]=p0.w;
        pk[k][4]=p1.x; pk[k][5]=p1.y; pk[k][6]=p1.z; pk[k][7]=p1.w;
        #pragma unroll
        for (int m = 0; m < NMODE; ++m) {
            ra[m] = pk[k][m] * ra[m] + rk[k][m];
            pa[m] = pk[k][m] * pa[m];
        }
    }

    #pragma unroll
    for (int d = 1; d < 64; d <<= 1) {
        #pragma unroll
        for (int m = 0; m < NMODE; ++m) {
            float plo = __shfl_up(pa[m], d);
            float rlo = __shfl_up(ra[m], d);
            if (lane >= d) {
                ra[m] = pa[m] * rlo + ra[m];
                pa[m] = pa[m] * plo;
            }
        }
    }

    float z[NMODE];
    #pragma unroll
    for (int m = 0; m < NMODE; ++m) {
        float zz = __shfl_up(ra[m], 1);
        z[m] = (lane == 0) ? 0.f : zz;
    }

    #pragma unroll
    for (int k = 0; k < K; ++k) {
        int c = lane * K + k;
        float4* rv = (float4*)(rp + (size_t)c * NMODE);
        rv[0] = make_float4(z[0], z[1], z[2], z[3]);
        rv[1] = make_float4(z[4], z[5], z[6], z[7]);
        #pragma unroll
        for (int m = 0; m < NMODE; ++m)
            z[m] = pk[k][m] * z[m] + rk[k][m];
    }
}

// ---------------------------------------------------------------------------
// Phase C: 256-thread block per GC chunks. corr_t[e] = sum_m caA[t,m]*Z[e,m];
// finalizes S and Q_sum planes. Pure algebra, coalesced plane traffic.
// ---------------------------------------------------------------------------
template <int L, int GC>
__global__ __launch_bounds__(256)
void phaseC(float* __restrict__ out,
            const float* __restrict__ partR,   // now Z [b,9,NC,8]
            const float* __restrict__ caA,     // [B,NC,L,8]
            int B) {
    constexpr int NC = T_LEN / L;
    const int tid  = threadIdx.x;
    const int ngrp = NC / GC;
    const int b  = blockIdx.x / ngrp;
    const int g  = blockIdx.x % ngrp;
    const int c0 = g * GC;

    __shared__ float s_Z[GC * 72];
    __shared__ float s_ca[GC * L * 8];

    for (int i = tid; i < GC * 72; i += 256) {
        int cl = i / 72, u = i % 72, e = u >> 3, m = u & 7;
        s_Z[i] = partR[((size_t)(b * 9 + e) * NC + c0 + cl) * 8 + m];
    }
    const float* ca = caA + ((size_t)b * NC + c0) * (L * 8);
    for (int i = tid; i < GC * L * 8; i += 256) s_ca[i] = ca[i];
    __syncthreads();

    const size_t nOut = (size_t)B * T_LEN * 9;
    float* o = out + ((size_t)b * T_LEN + (size_t)c0 * L) * 9;
    for (int i = tid; i < GC * L * 9; i += 256) {
        int t = i / 9, e = i - t * 9;
        int cl = t / L;
        const float* caT = &s_ca[t * 8];
        const float* zE  = &s_Z[cl * 72 + e * 8];
        float corr = 0.f;
        #pragma unroll
        for (int m = 0; m < NMODE; ++m) corr += caT[m] * zE[m];
        float qs = o[2 * nOut + i] + corr;
        o[i]            = o[nOut + i] + qs;   // S
        o[2 * nOut + i] = qs;                 // Q_sum
    }
}

// ---------------------------------------------------------------------------
extern "C" void kernel_launch(void* const* d_in, const int* in_sizes, int n_in,
                              void* d_out, int out_size, void* d_ws, size_t ws_size,
                              hipStream_t stream) {
    const float* Se = (const float*)d_in[0];
    const float* tt = (const float*)d_in[1];
    const float* pp = (const float*)d_in[2];
    float* out = (float*)d_out;

    int B = in_sizes[1] / T_LEN;

    constexpr int L   = 16;
    constexpr int NC  = T_LEN / L;    // 128
    constexpr int K   = NC / 64;      // 2
    constexpr int CPB = 8;            // chunks per phaseA block (576 thr)
    constexpr int GC  = 4;            // chunks per phaseC block

    float* partR = (float*)d_ws;                                  // B*9*NC*8
    float* partP = partR + (size_t)B * 9 * NC * 8;                // B*NC*8
    float* caA   = partP + (size_t)B * NC * 8;                    // B*NC*L*8

    int gridA = B * (NC / CPB);
    int gridB = (B * 9 * 64 + 255) / 256;
    int gridC = B * (NC / GC);

    phaseA<L, CPB><<<gridA, dim3(72 * CPB), 0, stream>>>(
        Se, tt, pp, out, partR, partP, caA, B);
    chunk_scan_wave<K><<<gridB, dim3(256), 0, stream>>>(partR, partP, B);
    phaseC<L, GC><<<gridC, dim3(256), 0, stream>>>(out, partR, caA, B);
}

// Round 9
// 112.490 us; speedup vs baseline: 11.8409x; 1.1600x over previous
//
#include <hip/hip_runtime.h>

#define T_LEN 2048
#define NMODE 8
#define NPP   17   // 8 tau + 9 g (g[0]=g_infy)

// ===========================================================================
// Phase A: block = 256 thr, G=8 chunks x L=16 steps (128 rows + 1 prev).
//  1) stage pp/t/Se (Se transposed [e][row]) into LDS, coalesced
//  2) row-parallel precompute: per (step,m) -> A,C into skewed LDS (no
//     redundancy, all exp/rcp here, conflict-free b128 layout)
//  3) threads 0..71 = (k,e): register-resident 8-mode scan, per step:
//     4x broadcast ds_read_b128 (prefetched) + 1 b32 read + 1 b32 write.
//     threads 72..255 concurrently write the S_infy plane.
// Outputs: S_infy plane (final), local-qsum plane (fixed by phaseC),
//          partR[b,e,c,m], partP[b,c,m], caA[b,c,s,m].
// ===========================================================================
template <int L, int G>
__global__ __launch_bounds__(256)
void phaseA(const float* __restrict__ Se,   // [B,T,3,3]
            const float* __restrict__ tt,   // [B,T]
            const float* __restrict__ pp,   // [B,T,17]
            float* __restrict__ out,        // [3,B,T,3,3]
            float* __restrict__ partR,      // [B,9,NC,8]
            float* __restrict__ partP,      // [B,NC,8]
            float* __restrict__ caA,        // [B,NC,L,8]
            int B) {
    constexpr int NC    = T_LEN / L;
    constexpr int NSTEP = G * L;          // 128
    constexpr int RW    = NSTEP + 1;      // 129 rows staged
    constexpr int NT    = 256;
    // LDS float offsets
    constexpr int RAW_SZ = RW * NPP;               // 2193
    constexpr int QT_SZ  = 9 * (NSTEP + 4);        // 1188 (transposed, padded)
    constexpr int CA_K   = L * 8 + 4;              // 132 (per-k skew)
    constexpr int UNION_SZ = (RAW_SZ > QT_SZ + 8 * CA_K) ? RAW_SZ
                                                         : (QT_SZ + 8 * CA_K);
    constexpr int AC_K  = L * 16 + 4;              // 260 dwords per chunk (skew 16B)
    constexpr int O_AC  = UNION_SZ;                // s_AC[G*AC_K]
    constexpr int O_ST  = O_AC + G * AC_K;         // s_S_T[9][NSTEP+4]
    constexpr int SROW  = NSTEP + 4;               // 132
    constexpr int O_T   = O_ST + 9 * SROW;         // s_t[RW]
    constexpr int O_INV = O_T + RW;                // s_inv[RW]
    constexpr int O_GI  = O_INV + RW;              // s_gi[RW]
    constexpr int TOTAL = O_GI + RW;

    __shared__ __align__(16) float sm[TOTAL];
    float* s_raw = sm;                    // union: raw inputs
    float* s_qT  = sm;                    // union: qsum transposed [e][t]
    float* s_ca  = sm + QT_SZ;            // union: cumA skewed [k][s][8]
    float* s_AC  = sm + O_AC;
    float* s_ST  = sm + O_ST;
    float* s_t   = sm + O_T;
    float* s_inv = sm + O_INV;
    float* s_gi  = sm + O_GI;

    const int tid  = threadIdx.x;
    const int ngrp = NC / G;
    const int b    = blockIdx.x / ngrp;
    const int grp  = blockIdx.x % ngrp;
    const int c0   = grp * G;
    const int base = c0 * L;
    const int off  = (base == 0) ? 0 : 1;
    const int r0   = (base == 0) ? 0 : base - 1;

    // ---- stage inputs ----
    {
        const float* pr = pp + ((size_t)b * T_LEN + r0) * NPP;
        for (int i = tid; i < RW * NPP; i += NT) s_raw[i] = pr[i];
        const float* sr = Se + ((size_t)b * T_LEN + r0) * 9;
        for (int i = tid; i < RW * 9; i += NT) {
            int r = i / 9, e = i - r * 9;
            s_ST[e * SROW + r] = sr[i];
        }
        const float* tr = tt + (size_t)b * T_LEN + r0;
        for (int i = tid; i < RW; i += NT) s_t[i] = tr[i];
    }
    __syncthreads();

    // ---- per-row 1/sum(g), g_infy/sum ----
    for (int i = tid; i < RW; i += NT) {
        float gs = 0.f;
        #pragma unroll
        for (int k = 8; k < NPP; ++k) gs += s_raw[i * NPP + k];
        float iv = __builtin_amdgcn_rcpf(gs);
        s_inv[i] = iv;
        s_gi[i]  = s_raw[i * NPP + 8] * iv;
    }
    __syncthreads();

    // ---- per-(step,mode) coefficients: all exp/rcp here ----
    for (int i = tid; i < NSTEP * 8; i += NT) {
        int m  = i & 7;
        int ts = i >> 3;
        int rc = ts + off;
        bool first = (base == 0) && (ts == 0);
        int rp = first ? rc : rc - 1;
        float tau_c = s_raw[rc * NPP + m];
        float tau_p = s_raw[rp * NPP + m];
        float gqh_c = 0.5f * s_raw[rc * NPP + 9 + m] * s_inv[rc];
        float gqh_p = 0.5f * s_raw[rp * NPP + 9 + m] * s_inv[rp];
        float t_c = s_t[rc];
        float t_p = first ? -s_t[1] : s_t[rp];
        float ee  = __expf((t_p - t_c) * __builtin_amdgcn_rcpf(tau_c + tau_p));
        int kk = ts / L, sl = ts % L;
        s_AC[kk * AC_K + sl * 16 + m]     = ee * ee;           // A
        s_AC[kk * AC_K + sl * 16 + 8 + m] = ee * (gqh_c + gqh_p); // C
    }
    __syncthreads();   // s_raw consumed; union becomes s_qT/s_ca

    const size_t nOut = (size_t)B * T_LEN * 9;

    if (tid < 72) {
        // ---- scan: thread (k,e), 8 modes in registers ----
        const int k  = tid / 9;
        const int e  = tid - k * 9;
        const int cg = c0 + k;
        float S_p = (cg == 0) ? 0.f : s_ST[e * SROW + (k * L + off - 1)];

        float Q[8] = {0,0,0,0,0,0,0,0};
        float cA[8] = {1,1,1,1,1,1,1,1};
        const float4* acp = (const float4*)(s_AC + k * AC_K);

        float4 a0 = acp[0], a1 = acp[1], c0v = acp[2], c1v = acp[3];
        #pragma unroll
        for (int s = 0; s < L; ++s) {
            float4 na0, na1, nc0, nc1;
            if (s < L - 1) {
                na0 = acp[4*s+4]; na1 = acp[4*s+5];
                nc0 = acp[4*s+6]; nc1 = acp[4*s+7];
            }
            float S_c = s_ST[e * SROW + (k * L + s + off)];
            float dS  = S_c - S_p;
            S_p = S_c;
            Q[0] = a0.x*Q[0] + c0v.x*dS;  Q[1] = a0.y*Q[1] + c0v.y*dS;
            Q[2] = a0.z*Q[2] + c0v.z*dS;  Q[3] = a0.w*Q[3] + c0v.w*dS;
            Q[4] = a1.x*Q[4] + c1v.x*dS;  Q[5] = a1.y*Q[5] + c1v.y*dS;
            Q[6] = a1.z*Q[6] + c1v.z*dS;  Q[7] = a1.w*Q[7] + c1v.w*dS;
            cA[0]*=a0.x; cA[1]*=a0.y; cA[2]*=a0.z; cA[3]*=a0.w;
            cA[4]*=a1.x; cA[5]*=a1.y; cA[6]*=a1.z; cA[7]*=a1.w;
            float qs = ((Q[0]+Q[1])+(Q[2]+Q[3])) + ((Q[4]+Q[5])+(Q[6]+Q[7]));
            s_qT[e * SROW + (k * L + s)] = qs;
            if (e == 0) {
                float4* cw = (float4*)(s_ca + k * CA_K + s * 8);
                cw[0] = make_float4(cA[0], cA[1], cA[2], cA[3]);
                cw[1] = make_float4(cA[4], cA[5], cA[6], cA[7]);
            }
            a0 = na0; a1 = na1; c0v = nc0; c1v = nc1;
        }

        float4* pr4 = (float4*)(partR + ((size_t)(b * 9 + e) * NC + cg) * 8);
        pr4[0] = make_float4(Q[0], Q[1], Q[2], Q[3]);
        pr4[1] = make_float4(Q[4], Q[5], Q[6], Q[7]);
        if (e == 0) {
            float4* pp4 = (float4*)(partP + ((size_t)b * NC + cg) * 8);
            pp4[0] = make_float4(cA[0], cA[1], cA[2], cA[3]);
            pp4[1] = make_float4(cA[4], cA[5], cA[6], cA[7]);
        }
    } else {
        // ---- threads 72..255: S_infy plane (coeff outputs only) ----
        float* o1 = out + nOut + ((size_t)b * T_LEN + base) * 9;
        for (int i = tid - 72; i < NSTEP * 9; i += 184) {
            int t = i / 9, e = i - t * 9;
            int rc = t + off;
            o1[i] = s_gi[rc] * s_ST[e * SROW + rc];
        }
    }
    __syncthreads();

    // ---- bulk coalesced writes: local-qsum plane + caA ----
    float* o2 = out + 2 * nOut + ((size_t)b * T_LEN + base) * 9;
    for (int i = tid; i < NSTEP * 9; i += NT) {
        int t = i / 9, e = i - t * 9;
        o2[i] = s_qT[e * SROW + t];
    }
    float* ca = caA + ((size_t)b * NC + c0) * (L * 8);
    for (int i = tid; i < NSTEP * 8; i += NT) {
        int t = i >> 3, m = i & 7;
        int kk = t / L, sl = t % L;
        ca[i] = s_ca[kk * CA_K + sl * 8 + m];
    }
}

// ===========================================================================
// Phase B: inter-chunk scan, ONE WAVE per (b,e) (proven R4/R7/R8). Converts
// partR in place from local chunk results to entering states Z (exclusive).
// ===========================================================================
template <int K>
__global__ __launch_bounds__(256)
void chunk_scan_wave(float* __restrict__ R, const float* __restrict__ P,
                     int B) {
    constexpr int NC = K * 64;
    int gtid = blockIdx.x * blockDim.x + threadIdx.x;
    int wid  = gtid >> 6;
    int lane = gtid & 63;
    if (wid >= B * 9) return;
    int e = wid % 9;
    int b = wid / 9;

    float* rp       = R + ((size_t)(b * 9 + e) * NC) * NMODE;
    const float* pq = P + ((size_t)b * NC) * NMODE;

    float pk[K][NMODE], rk[K][NMODE];
    float pa[NMODE], ra[NMODE];
    #pragma unroll
    for (int m = 0; m < NMODE; ++m) { pa[m] = 1.f; ra[m] = 0.f; }

    #pragma unroll
    for (int k = 0; k < K; ++k) {
        int c = lane * K + k;
        const float4* rv = (const float4*)(rp + (size_t)c * NMODE);
        const float4* pv = (const float4*)(pq + (size_t)c * NMODE);
        float4 r0 = rv[0], r1 = rv[1], p0 = pv[0], p1 = pv[1];
        rk[k][0]=r0.x; rk[k][1]=r0.y; rk[k][2]=r0.z; rk[k][3]=r0.w;
        rk[k][4]=r1.x; rk[k][5]=r1.y; rk[k][6]=r1.z; rk[k][7]=r1.w;
        pk[k][0]=p0.x; pk[k][1]=p0.y; pk[k][2]=p0.z; pk[k][3]=p0.w;
        pk[k][4]=p1.x; pk[k][5]=p1.y; pk[k][6]=p1.z; pk[k][7]=p1.w;
        #pragma unroll
        for (int m = 0; m < NMODE; ++m) {
            ra[m] = pk[k][m] * ra[m] + rk[k][m];
            pa[m] = pk[k][m] * pa[m];
        }
    }

    #pragma unroll
    for (int d = 1; d < 64; d <<= 1) {
        #pragma unroll
        for (int m = 0; m < NMODE; ++m) {
            float plo = __shfl_up(pa[m], d);
            float rlo = __shfl_up(ra[m], d);
            if (lane >= d) {
                ra[m] = pa[m] * rlo + ra[m];
                pa[m] = pa[m] * plo;
            }
        }
    }

    float z[NMODE];
    #pragma unroll
    for (int m = 0; m < NMODE; ++m) {
        float zz = __shfl_up(ra[m], 1);
        z[m] = (lane == 0) ? 0.f : zz;
    }

    #pragma unroll
    for (int k = 0; k < K; ++k) {
        int c = lane * K + k;
        float4* rv = (float4*)(rp + (size_t)c * NMODE);
        rv[0] = make_float4(z[0], z[1], z[2], z[3]);
        rv[1] = make_float4(z[4], z[5], z[6], z[7]);
        #pragma unroll
        for (int m = 0; m < NMODE; ++m)
            z[m] = pk[k][m] * z[m] + rk[k][m];
    }
}

// ===========================================================================
// Phase C: 256-thread block per GC chunks. corr_t[e] = sum_m caA[t,m]*Z[e,m];
// finalizes S and Q_sum planes. Pure algebra, coalesced plane traffic.
// ===========================================================================
template <int L, int GC>
__global__ __launch_bounds__(256)
void phaseC(float* __restrict__ out,
            const float* __restrict__ partR,   // now Z [b,9,NC,8]
            const float* __restrict__ caA,     // [B,NC,L,8]
            int B) {
    constexpr int NC = T_LEN / L;
    const int tid  = threadIdx.x;
    const int ngrp = NC / GC;
    const int b  = blockIdx.x / ngrp;
    const int g  = blockIdx.x % ngrp;
    const int c0 = g * GC;

    __shared__ float s_Z[GC * 72];
    __shared__ float s_ca[GC * L * 8];

    for (int i = tid; i < GC * 72; i += 256) {
        int cl = i / 72, u = i % 72, e = u >> 3, m = u & 7;
        s_Z[i] = partR[((size_t)(b * 9 + e) * NC + c0 + cl) * 8 + m];
    }
    const float* ca = caA + ((size_t)b * NC + c0) * (L * 8);
    for (int i = tid; i < GC * L * 8; i += 256) s_ca[i] = ca[i];
    __syncthreads();

    const size_t nOut = (size_t)B * T_LEN * 9;
    float* o = out + ((size_t)b * T_LEN + (size_t)c0 * L) * 9;
    for (int i = tid; i < GC * L * 9; i += 256) {
        int t = i / 9, e = i - t * 9;
        int cl = t / L;
        const float* caT = &s_ca[t * 8];
        const float* zE  = &s_Z[cl * 72 + e * 8];
        float corr = 0.f;
        #pragma unroll
        for (int m = 0; m < NMODE; ++m) corr += caT[m] * zE[m];
        float qs = o[2 * nOut + i] + corr;
        o[i]            = o[nOut + i] + qs;   // S
        o[2 * nOut + i] = qs;                 // Q_sum
    }
}

// ===========================================================================
extern "C" void kernel_launch(void* const* d_in, const int* in_sizes, int n_in,
                              void* d_out, int out_size, void* d_ws, size_t ws_size,
                              hipStream_t stream) {
    const float* Se = (const float*)d_in[0];
    const float* tt = (const float*)d_in[1];
    const float* pp = (const float*)d_in[2];
    float* out = (float*)d_out;

    int B = in_sizes[1] / T_LEN;

    constexpr int L  = 16;
    constexpr int NC = T_LEN / L;     // 128
    constexpr int K  = NC / 64;       // 2
    constexpr int G  = 8;             // chunks per phaseA block
    constexpr int GC = 4;             // chunks per phaseC block

    float* partR = (float*)d_ws;                                  // B*9*NC*8
    float* partP = partR + (size_t)B * 9 * NC * 8;                // B*NC*8
    float* caA   = partP + (size_t)B * NC * 8;                    // B*NC*L*8

    int gridA = B * (NC / G);
    int gridB = (B * 9 * 64 + 255) / 256;
    int gridC = B * (NC / GC);

    phaseA<L, G><<<gridA, dim3(256), 0, stream>>>(
        Se, tt, pp, out, partR, partP, caA, B);
    chunk_scan_wave<K><<<gridB, dim3(256), 0, stream>>>(partR, partP, B);
    phaseC<L, GC><<<gridC, dim3(256), 0, stream>>>(out, partR, caA, B);
}

// Round 10
// 108.399 us; speedup vs baseline: 12.2877x; 1.0377x over previous
//
#include <hip/hip_runtime.h>

#define T_LEN 2048
#define NMODE 8
#define NPP   17   // 8 tau + 9 g (g[0]=g_infy)

// ===========================================================================
// Phase A: block = 256 thr, G=8 chunks x L=16 steps (128 rows + 1 prev).
//  1) stage pp/t/Se (Se transposed [e][row]) into LDS, coalesced
//  2) row-parallel coeff pass: per (step,m) -> A,C into skewed LDS
//  3) concurrent: tid<72 (k,e) register-scan (4xb128 + 1 b32/step);
//     tid 72..191 write S_infy plane; tid 192..255 = (k,m) cumA mini-pass
//     (serial product of A in LDS, writes partP).
// Outputs: S_infy plane (final), local-qsum plane (fixed by phaseC),
//          partR[b,e,c,m], partP[b,c,m], caA[b,c,s,m].
// ===========================================================================
template <int L, int G>
__global__ __launch_bounds__(256)
void phaseA(const float* __restrict__ Se,   // [B,T,3,3]
            const float* __restrict__ tt,   // [B,T]
            const float* __restrict__ pp,   // [B,T,17]
            float* __restrict__ out,        // [3,B,T,3,3]
            float* __restrict__ partR,      // [B,9,NC,8]
            float* __restrict__ partP,      // [B,NC,8]
            float* __restrict__ caA,        // [B,NC,L,8]
            int B) {
    constexpr int NC    = T_LEN / L;
    constexpr int NSTEP = G * L;          // 128
    constexpr int RW    = NSTEP + 1;      // 129
    constexpr int NT    = 256;
    constexpr int RAW_SZ = RW * NPP;               // 2193
    constexpr int QT_SZ  = 9 * (NSTEP + 4);        // 1188
    constexpr int CA_K   = L * 8 + 4;              // 132
    constexpr int UNION_SZ = (RAW_SZ > QT_SZ + G * CA_K) ? RAW_SZ
                                                         : (QT_SZ + G * CA_K);
    constexpr int AC_K  = L * 16 + 4;              // 260
    constexpr int O_AC  = UNION_SZ;
    constexpr int SROW  = NSTEP + 4;               // 132
    constexpr int O_ST  = O_AC + G * AC_K;
    constexpr int O_T   = O_ST + 9 * SROW;
    constexpr int O_INV = O_T + RW;
    constexpr int O_GI  = O_INV + RW;
    constexpr int TOTAL = O_GI + RW;

    __shared__ __align__(16) float sm[TOTAL];
    float* s_raw = sm;                    // union: raw inputs
    float* s_qT  = sm;                    // union: qsum transposed [e][t]
    float* s_ca  = sm + QT_SZ;            // union: cumA skewed [k][s][8]
    float* s_AC  = sm + O_AC;
    float* s_ST  = sm + O_ST;
    float* s_t   = sm + O_T;
    float* s_inv = sm + O_INV;
    float* s_gi  = sm + O_GI;

    const int tid  = threadIdx.x;
    const int ngrp = NC / G;
    const int b    = blockIdx.x / ngrp;
    const int grp  = blockIdx.x % ngrp;
    const int c0   = grp * G;
    const int base = c0 * L;
    const int off  = (base == 0) ? 0 : 1;
    const int r0   = (base == 0) ? 0 : base - 1;

    // ---- stage inputs ----
    {
        const float* pr = pp + ((size_t)b * T_LEN + r0) * NPP;
        for (int i = tid; i < RW * NPP; i += NT) s_raw[i] = pr[i];
        const float* sr = Se + ((size_t)b * T_LEN + r0) * 9;
        for (int i = tid; i < RW * 9; i += NT) {
            int r = i / 9, e = i - r * 9;
            s_ST[e * SROW + r] = sr[i];
        }
        const float* tr = tt + (size_t)b * T_LEN + r0;
        for (int i = tid; i < RW; i += NT) s_t[i] = tr[i];
    }
    __syncthreads();

    // ---- per-row 1/sum(g), g_infy/sum ----
    for (int i = tid; i < RW; i += NT) {
        float gs = 0.f;
        #pragma unroll
        for (int k = 8; k < NPP; ++k) gs += s_raw[i * NPP + k];
        float iv = __builtin_amdgcn_rcpf(gs);
        s_inv[i] = iv;
        s_gi[i]  = s_raw[i * NPP + 8] * iv;
    }
    __syncthreads();

    // ---- per-(step,mode) coefficients: all exp/rcp here ----
    for (int i = tid; i < NSTEP * 8; i += NT) {
        int m  = i & 7;
        int ts = i >> 3;
        int rc = ts + off;
        bool first = (base == 0) && (ts == 0);
        int rp = first ? rc : rc - 1;
        float tau_c = s_raw[rc * NPP + m];
        float tau_p = s_raw[rp * NPP + m];
        float gqh_c = 0.5f * s_raw[rc * NPP + 9 + m] * s_inv[rc];
        float gqh_p = 0.5f * s_raw[rp * NPP + 9 + m] * s_inv[rp];
        float t_c = s_t[rc];
        float t_p = first ? -s_t[1] : s_t[rp];
        float ee  = __expf((t_p - t_c) * __builtin_amdgcn_rcpf(tau_c + tau_p));
        int kk = ts / L, sl = ts % L;
        s_AC[kk * AC_K + sl * 16 + m]     = ee * ee;              // A
        s_AC[kk * AC_K + sl * 16 + 8 + m] = ee * (gqh_c + gqh_p); // C
    }
    __syncthreads();   // s_raw consumed; union becomes s_qT/s_ca

    const size_t nOut = (size_t)B * T_LEN * 9;

    if (tid < 72) {
        // ---- scan: thread (k,e), 8 modes in registers ----
        const int k  = tid / 9;
        const int e  = tid - k * 9;
        const int cg = c0 + k;

        // preload S values, build dS in registers
        float dS[L];
        {
            float Sv[L + 1];
            Sv[0] = (cg == 0) ? 0.f : s_ST[e * SROW + (k * L + off - 1)];
            #pragma unroll
            for (int s = 0; s < L; ++s)
                Sv[s + 1] = s_ST[e * SROW + (k * L + s + off)];
            #pragma unroll
            for (int s = 0; s < L; ++s) dS[s] = Sv[s + 1] - Sv[s];
        }

        float Q[8] = {0,0,0,0,0,0,0,0};
        const float4* acp = (const float4*)(s_AC + k * AC_K);

        float4 a0 = acp[0], a1 = acp[1], c0v = acp[2], c1v = acp[3];
        #pragma unroll
        for (int s = 0; s < L; ++s) {
            float4 na0, na1, nc0, nc1;
            if (s < L - 1) {
                na0 = acp[4*s+4]; na1 = acp[4*s+5];
                nc0 = acp[4*s+6]; nc1 = acp[4*s+7];
            }
            float d = dS[s];
            Q[0] = a0.x*Q[0] + c0v.x*d;  Q[1] = a0.y*Q[1] + c0v.y*d;
            Q[2] = a0.z*Q[2] + c0v.z*d;  Q[3] = a0.w*Q[3] + c0v.w*d;
            Q[4] = a1.x*Q[4] + c1v.x*d;  Q[5] = a1.y*Q[5] + c1v.y*d;
            Q[6] = a1.z*Q[6] + c1v.z*d;  Q[7] = a1.w*Q[7] + c1v.w*d;
            float qs = ((Q[0]+Q[1])+(Q[2]+Q[3])) + ((Q[4]+Q[5])+(Q[6]+Q[7]));
            s_qT[e * SROW + (k * L + s)] = qs;
            a0 = na0; a1 = na1; c0v = nc0; c1v = nc1;
        }

        float4* pr4 = (float4*)(partR + ((size_t)(b * 9 + e) * NC + cg) * 8);
        pr4[0] = make_float4(Q[0], Q[1], Q[2], Q[3]);
        pr4[1] = make_float4(Q[4], Q[5], Q[6], Q[7]);
    } else if (tid < 192) {
        // ---- threads 72..191: S_infy plane ----
        float* o1 = out + nOut + ((size_t)b * T_LEN + base) * 9;
        for (int i = tid - 72; i < NSTEP * 9; i += 120) {
            int t = i / 9, e = i - t * 9;
            int rc = t + off;
            o1[i] = s_gi[rc] * s_ST[e * SROW + rc];
        }
    } else {
        // ---- threads 192..255 = (k,m): cumA mini-pass + partP ----
        const int u = tid - 192;
        const int k = u >> 3;
        const int m = u & 7;
        float c = 1.f;
        #pragma unroll
        for (int s = 0; s < L; ++s) {
            c *= s_AC[k * AC_K + s * 16 + m];
            s_ca[k * CA_K + s * 8 + m] = c;
        }
        partP[((size_t)b * NC + (c0 + k)) * 8 + m] = c;
    }
    __syncthreads();

    // ---- bulk coalesced writes: local-qsum plane (f4) + caA (f4) ----
    float* o2 = out + 2 * nOut + ((size_t)b * T_LEN + base) * 9;
    for (int i4 = tid; i4 < NSTEP * 9 / 4; i4 += NT) {
        int i = i4 * 4;
        float4 v;
        {
            int t0i = i / 9,     e0i = i - t0i * 9;
            int t1i = (i+1) / 9, e1i = (i+1) - t1i * 9;
            int t2i = (i+2) / 9, e2i = (i+2) - t2i * 9;
            int t3i = (i+3) / 9, e3i = (i+3) - t3i * 9;
            v.x = s_qT[e0i * SROW + t0i];
            v.y = s_qT[e1i * SROW + t1i];
            v.z = s_qT[e2i * SROW + t2i];
            v.w = s_qT[e3i * SROW + t3i];
        }
        ((float4*)o2)[i4] = v;
    }
    float* ca = caA + ((size_t)b * NC + c0) * (L * 8);
    {
        // one float4 per thread: tid -> (k = tid/32, j = tid%32)
        int k = tid >> 5, j = tid & 31;
        const float4* src = (const float4*)(s_ca + k * CA_K);
        ((float4*)(ca + k * L * 8))[j] = src[j];
    }
}

// ===========================================================================
// Phase B: inter-chunk scan, ONE WAVE per (b,e) (proven R4/R7-R9). Converts
// partR in place from local chunk results to entering states Z (exclusive).
// ===========================================================================
template <int K>
__global__ __launch_bounds__(256)
void chunk_scan_wave(float* __restrict__ R, const float* __restrict__ P,
                     int B) {
    constexpr int NC = K * 64;
    int gtid = blockIdx.x * blockDim.x + threadIdx.x;
    int wid  = gtid >> 6;
    int lane = gtid & 63;
    if (wid >= B * 9) return;
    int e = wid % 9;
    int b = wid / 9;

    float* rp       = R + ((size_t)(b * 9 + e) * NC) * NMODE;
    const float* pq = P + ((size_t)b * NC) * NMODE;

    float pk[K][NMODE], rk[K][NMODE];
    float pa[NMODE], ra[NMODE];
    #pragma unroll
    for (int m = 0; m < NMODE; ++m) { pa[m] = 1.f; ra[m] = 0.f; }

    #pragma unroll
    for (int k = 0; k < K; ++k) {
        int c = lane * K + k;
        const float4* rv = (const float4*)(rp + (size_t)c * NMODE);
        const float4* pv = (const float4*)(pq + (size_t)c * NMODE);
        float4 r0 = rv[0], r1 = rv[1], p0 = pv[0], p1 = pv[1];
        rk[k][0]=r0.x; rk[k][1]=r0.y; rk[k][2]=r0.z; rk[k][3]=r0.w;
        rk[k][4]=r1.x; rk[k][5]=r1.y; rk[k][6]=r1.z; rk[k][7]=r1.w;
        pk[k][0]=p0.x; pk[k][1]=p0.y; pk[k][2]=p0.z; pk[k][3]=p0.w;
        pk[k][4]=p1.x; pk[k][5]=p1.y; pk[k][6]=p1.z; pk[k][7]=p1.w;
        #pragma unroll
        for (int m = 0; m < NMODE; ++m) {
            ra[m] = pk[k][m] * ra[m] + rk[k][m];
            pa[m] = pk[k][m] * pa[m];
        }
    }

    #pragma unroll
    for (int d = 1; d < 64; d <<= 1) {
        #pragma unroll
        for (int m = 0; m < NMODE; ++m) {
            float plo = __shfl_up(pa[m], d);
            float rlo = __shfl_up(ra[m], d);
            if (lane >= d) {
                ra[m] = pa[m] * rlo + ra[m];
                pa[m] = pa[m] * plo;
            }
        }
    }

    float z[NMODE];
    #pragma unroll
    for (int m = 0; m < NMODE; ++m) {
        float zz = __shfl_up(ra[m], 1);
        z[m] = (lane == 0) ? 0.f : zz;
    }

    #pragma unroll
    for (int k = 0; k < K; ++k) {
        int c = lane * K + k;
        float4* rv = (float4*)(rp + (size_t)c * NMODE);
        rv[0] = make_float4(z[0], z[1], z[2], z[3]);
        rv[1] = make_float4(z[4], z[5], z[6], z[7]);
        #pragma unroll
        for (int m = 0; m < NMODE; ++m)
            z[m] = pk[k][m] * z[m] + rk[k][m];
    }
}

// ===========================================================================
// Phase C: 256-thread block per GC chunks, float4 plane traffic.
// corr_t[e] = sum_m caA[t,m]*Z[e,m]; finalizes S and Q_sum planes.
// ===========================================================================
template <int L, int GC>
__global__ __launch_bounds__(256)
void phaseC(float* __restrict__ out,
            const float* __restrict__ partR,   // now Z [b,9,NC,8]
            const float* __restrict__ caA,     // [B,NC,L,8]
            int B) {
    constexpr int NC = T_LEN / L;
    constexpr int NE = GC * L * 9;             // elements per block
    const int tid  = threadIdx.x;
    const int ngrp = NC / GC;
    const int b  = blockIdx.x / ngrp;
    const int g  = blockIdx.x % ngrp;
    const int c0 = g * GC;

    __shared__ float s_Z[GC * 72];
    __shared__ __align__(16) float s_ca[GC * L * 8];

    for (int i = tid; i < GC * 72; i += 256) {
        int cl = i / 72, u = i % 72, e = u >> 3, m = u & 7;
        s_Z[i] = partR[((size_t)(b * 9 + e) * NC + c0 + cl) * 8 + m];
    }
    {
        const float4* ca4 = (const float4*)(caA + ((size_t)b * NC + c0) * (L * 8));
        for (int i = tid; i < GC * L * 2; i += 256)
            ((float4*)s_ca)[i] = ca4[i];
    }
    __syncthreads();

    const size_t nOut = (size_t)B * T_LEN * 9;
    float* o = out + ((size_t)b * T_LEN + (size_t)c0 * L) * 9;
    const float4* sf4 = (const float4*)(o + nOut);
    float4* s4 = (float4*)o;
    float4* q4 = (float4*)(o + 2 * nOut);

    for (int i4 = tid; i4 < NE / 4; i4 += 256) {
        int i = i4 * 4;
        float4 qv = q4[i4];
        float4 fv = sf4[i4];
        float corr[4];
        #pragma unroll
        for (int j = 0; j < 4; ++j) {
            int t = (i + j) / 9, e = (i + j) - t * 9;
            int cl = t / L;
            const float* caT = &s_ca[t * 8];
            const float* zE  = &s_Z[cl * 72 + e * 8];
            float cr = 0.f;
            #pragma unroll
            for (int m = 0; m < NMODE; ++m) cr += caT[m] * zE[m];
            corr[j] = cr;
        }
        float4 qn = make_float4(qv.x + corr[0], qv.y + corr[1],
                                qv.z + corr[2], qv.w + corr[3]);
        q4[i4] = qn;
        s4[i4] = make_float4(fv.x + qn.x, fv.y + qn.y,
                             fv.z + qn.z, fv.w + qn.w);
    }
}

// ===========================================================================
extern "C" void kernel_launch(void* const* d_in, const int* in_sizes, int n_in,
                              void* d_out, int out_size, void* d_ws, size_t ws_size,
                              hipStream_t stream) {
    const float* Se = (const float*)d_in[0];
    const float* tt = (const float*)d_in[1];
    const float* pp = (const float*)d_in[2];
    float* out = (float*)d_out;

    int B = in_sizes[1] / T_LEN;

    constexpr int L  = 16;
    constexpr int NC = T_LEN / L;     // 128
    constexpr int K  = NC / 64;       // 2
    constexpr int G  = 8;             // chunks per phaseA block
    constexpr int GC = 8;             // chunks per phaseC block

    float* partR = (float*)d_ws;                                  // B*9*NC*8
    float* partP = partR + (size_t)B * 9 * NC * 8;                // B*NC*8
    float* caA   = partP + (size_t)B * NC * 8;                    // B*NC*L*8

    int gridA = B * (NC / G);
    int gridB = (B * 9 * 64 + 255) / 256;
    int gridC = B * (NC / GC);

    phaseA<L, G><<<gridA, dim3(256), 0, stream>>>(
        Se, tt, pp, out, partR, partP, caA, B);
    chunk_scan_wave<K><<<gridB, dim3(256), 0, stream>>>(partR, partP, B);
    phaseC<L, GC><<<gridC, dim3(256), 0, stream>>>(out, partR, caA, B);
}